// Round 2
// baseline (190373.279 us; speedup 1.0000x reference)
//
#include <hip/hip_runtime.h>
#include <hip/hip_bf16.h>

// ---------------------------------------------------------------------------
// extract person slice: x [N,C,T,V,M=2] (chunk offset applied) -> xp contiguous
// ---------------------------------------------------------------------------
__global__ void extract_person(const float* __restrict__ x, float* __restrict__ xp,
                               int m, size_t total) {
    size_t i = (size_t)blockIdx.x * blockDim.x + threadIdx.x;
    if (i >= total) return;
    xp[i] = x[i * 2 + m];
}

// ---------------------------------------------------------------------------
// direct conv (stride 2) + optional conv-bias + BN affine + ReLU
// one thread per output element (n, oc, oy, ox), ox fastest
// ---------------------------------------------------------------------------
template <int K, int P>
__global__ __launch_bounds__(256) void conv_bn_relu(
    const float* __restrict__ in, const float* __restrict__ w,
    const float* __restrict__ cbias, const float* __restrict__ gam,
    const float* __restrict__ bet, float* __restrict__ out,
    int N, int Cin, int Hin, int Win, int Cout, int Hout, int Wout) {
    size_t idx = (size_t)blockIdx.x * blockDim.x + threadIdx.x;
    size_t total = (size_t)N * Cout * Hout * Wout;
    if (idx >= total) return;
    int ox = idx % Wout;
    size_t t = idx / Wout;
    int oy = t % Hout; t /= Hout;
    int oc = t % Cout;
    int n  = t / Cout;

    const float* wp = w + (size_t)oc * Cin * K * K;
    const float* ip = in + (size_t)n * Cin * Hin * Win;
    int iy0 = oy * 2 - P, ix0 = ox * 2 - P;

    float sum = 0.f;
    for (int ic = 0; ic < Cin; ++ic) {
        const float* iplane = ip + (size_t)ic * Hin * Win;
        const float* wk = wp + ic * K * K;
#pragma unroll
        for (int ky = 0; ky < K; ++ky) {
            int iy = iy0 + ky;
            if ((unsigned)iy >= (unsigned)Hin) continue;
            const float* row = iplane + (size_t)iy * Win;
#pragma unroll
            for (int kx = 0; kx < K; ++kx) {
                int ix = ix0 + kx;
                if ((unsigned)ix < (unsigned)Win)
                    sum = fmaf(row[ix], wk[ky * K + kx], sum);
            }
        }
    }
    if (cbias) sum += cbias[oc];
    sum = sum * gam[oc] + bet[oc];
    out[idx] = fmaxf(sum, 0.f);
}

// ---------------------------------------------------------------------------
// 2x2 maxpool stride 2
// ---------------------------------------------------------------------------
__global__ void maxpool2(const float* __restrict__ in, float* __restrict__ out,
                         int NC, int H, int W) {
    int Ho = H >> 1, Wo = W >> 1;
    size_t idx = (size_t)blockIdx.x * blockDim.x + threadIdx.x;
    size_t total = (size_t)NC * Ho * Wo;
    if (idx >= total) return;
    int ox = idx % Wo;
    size_t t = idx / Wo;
    int oy = t % Ho;
    int nc = t / Ho;
    const float* p = in + ((size_t)nc * H + oy * 2) * W + ox * 2;
    float v = fmaxf(fmaxf(p[0], p[1]), fmaxf(p[W], p[W + 1]));
    out[idx] = v;
}

// ---------------------------------------------------------------------------
// generic row-dot linear: out[n*Ncols+j] = X[n,:] . W[j,:] + bias[j]
// one block (256 thr) per output scalar; K % 4 == 0
// ---------------------------------------------------------------------------
__global__ __launch_bounds__(256) void linear_kernel(
    const float* __restrict__ X, const float* __restrict__ W,
    const float* __restrict__ bias, float* __restrict__ out, int K, int Ncols) {
    int n = blockIdx.x / Ncols;
    int j = blockIdx.x % Ncols;
    const float4* x4 = reinterpret_cast<const float4*>(X + (size_t)n * K);
    const float4* w4 = reinterpret_cast<const float4*>(W + (size_t)j * K);
    int K4 = K >> 2;
    float s = 0.f;
    for (int k = threadIdx.x; k < K4; k += blockDim.x) {
        float4 a = x4[k], b = w4[k];
        s = fmaf(a.x, b.x, s);
        s = fmaf(a.y, b.y, s);
        s = fmaf(a.z, b.z, s);
        s = fmaf(a.w, b.w, s);
    }
#pragma unroll
    for (int off = 32; off > 0; off >>= 1) s += __shfl_down(s, off, 64);
    __shared__ float lds[4];
    int lane = threadIdx.x & 63, wv = threadIdx.x >> 6;
    if (lane == 0) lds[wv] = s;
    __syncthreads();
    if (threadIdx.x == 0)
        out[blockIdx.x] = lds[0] + lds[1] + lds[2] + lds[3] + bias[j];
}

// ---------------------------------------------------------------------------
// build per-sample rotation matrix + bias vector from o[Nc,6]
// ---------------------------------------------------------------------------
__global__ void make_rot(const float* __restrict__ o6, float* __restrict__ R,
                         float* __restrict__ bv, int Nc) {
    int n = threadIdx.x;
    if (n >= Nc) return;
    const float PI = 3.14159265358979323846f;
    float a0 = o6[n * 6 + 0] * PI, a1 = o6[n * 6 + 1] * PI, a2 = o6[n * 6 + 2] * PI;
    float c0 = cosf(a0), c1 = cosf(a1), c2 = cosf(a2);
    float s0 = sinf(a0), s1 = sinf(a1), s2 = sinf(a2);
    float Rx[9] = {1, 0, 0, 0, c0, s0, 0, -s0, c0};
    float Ry[9] = {c1, 0, -s1, 0, 1, 0, s1, 0, c1};
    float Rz[9] = {c2, s2, 0, -s2, c2, 0, 0, 0, 1};
    float M[9], Rm[9];
#pragma unroll
    for (int i = 0; i < 3; ++i)
#pragma unroll
        for (int j = 0; j < 3; ++j) {
            float acc = 0.f;
#pragma unroll
            for (int k = 0; k < 3; ++k) acc = fmaf(Ry[i * 3 + k], Rz[k * 3 + j], acc);
            M[i * 3 + j] = acc;
        }
#pragma unroll
    for (int i = 0; i < 3; ++i)
#pragma unroll
        for (int j = 0; j < 3; ++j) {
            float acc = 0.f;
#pragma unroll
            for (int k = 0; k < 3; ++k) acc = fmaf(Rx[i * 3 + k], M[k * 3 + j], acc);
            Rm[i * 3 + j] = acc;
        }
    const float MINV = -3.602826f;
    float v0 = MINV - o6[n * 6 + 3];
    float v1 = MINV - o6[n * 6 + 4];
    float v2 = MINV - o6[n * 6 + 5];
#pragma unroll
    for (int i = 0; i < 3; ++i) {
        float sh = Rm[i * 3 + 0] * v0 + Rm[i * 3 + 1] * v1 + Rm[i * 3 + 2] * v2;
        bv[n * 3 + i] = 255.f * (sh - MINV) / 8.812765f;
        R[n * 9 + i * 3 + 0] = Rm[i * 3 + 0];
        R[n * 9 + i * 3 + 1] = Rm[i * 3 + 1];
        R[n * 9 + i * 3 + 2] = Rm[i * 3 + 2];
    }
}

// ---------------------------------------------------------------------------
// z[n,i,p] = sum_j R[n,i,j]*xp[n,j,p] + bias[n,i]   (p over H*W)
// ---------------------------------------------------------------------------
__global__ void rot_apply(const float* __restrict__ xp, const float* __restrict__ R,
                          const float* __restrict__ bv, float* __restrict__ z,
                          int HW, size_t total) {
    size_t idx = (size_t)blockIdx.x * blockDim.x + threadIdx.x;
    if (idx >= total) return;
    int p = idx % HW;
    size_t t = idx / HW;
    int i = t % 3;
    int n = t / 3;
    const float* xb = xp + (size_t)n * 3 * HW + p;
    float r0 = R[n * 9 + i * 3 + 0], r1 = R[n * 9 + i * 3 + 1], r2 = R[n * 9 + i * 3 + 2];
    z[idx] = fmaf(r0, xb[0], fmaf(r1, xb[(size_t)HW], fmaf(r2, xb[(size_t)2 * HW], bv[n * 3 + i])));
}

// ---------------------------------------------------------------------------
// elementwise copy / max-combine
// ---------------------------------------------------------------------------
__global__ void copy_kernel(const float* __restrict__ a, float* __restrict__ o, size_t n) {
    size_t i = (size_t)blockIdx.x * blockDim.x + threadIdx.x;
    if (i < n) o[i] = a[i];
}
__global__ void max_kernel(const float* __restrict__ a, float* __restrict__ o, size_t n) {
    size_t i = (size_t)blockIdx.x * blockDim.x + threadIdx.x;
    if (i < n) o[i] = fmaxf(o[i], a[i]);
}

// ---------------------------------------------------------------------------
static inline int nblk(size_t total, int bs) { return (int)((total + bs - 1) / bs); }

extern "C" void kernel_launch(void* const* d_in, const int* in_sizes, int n_in,
                              void* d_out, int out_size, void* d_ws, size_t ws_size,
                              hipStream_t stream) {
    const float* x   = (const float*)d_in[0];
    const float* w1  = (const float*)d_in[1];
    const float* b1  = (const float*)d_in[2];
    const float* g1  = (const float*)d_in[3];
    const float* be1 = (const float*)d_in[4];
    const float* w2  = (const float*)d_in[5];
    const float* b2  = (const float*)d_in[6];
    const float* g2  = (const float*)d_in[7];
    const float* be2 = (const float*)d_in[8];
    const float* fw  = (const float*)d_in[9];
    const float* fb  = (const float*)d_in[10];
    const float* bw[5], *bg[5], *bb[5];
    for (int i = 0; i < 5; ++i) {
        bw[i] = (const float*)d_in[11 + 3 * i];
        bg[i] = (const float*)d_in[12 + 3 * i];
        bb[i] = (const float*)d_in[13 + 3 * i];
    }
    const float* lw = (const float*)d_in[26];
    const float* lb = (const float*)d_in[27];
    float* out = (float*)d_out;

    const int N = 32;
    // per-sample sizes (floats)
    const size_t S_X  = (size_t)3 * 224 * 224;      // 150,528
    const size_t S_B1 = (size_t)128 * 112 * 112;    // 1,605,632 (also >= all backbone acts)
    const size_t S_B2 = (size_t)256 * 56 * 56;      // 802,816
    const size_t S_P  = (size_t)128 * 28 * 28;      // 100,352
    const size_t S_PM = (size_t)2048 * 7 * 7;       // 100,352
    const size_t per_sample = 2 * S_X + S_B1 + S_B2 + S_P;   // 2,809,856
    const size_t fixed = (size_t)N * S_PM + 1024;            // PM + rot scratch

    // pick largest power-of-two chunk that fits ws
    size_t ws_floats = ws_size / sizeof(float);
    int Nc = N;
    while (Nc > 1 && (size_t)Nc * per_sample + fixed > ws_floats) Nc >>= 1;

    float* ws = (float*)d_ws;
    float* PM  = ws;                      // [N,2048,7,7] person-max accumulator
    float* O6  = PM + (size_t)N * S_PM;   // [Nc,6]
    float* Rm  = O6 + 256;                // [Nc,9]
    float* BV  = Rm + 384;                // [Nc,3]
    float* X   = PM + fixed;              // chunk buffers
    float* Z   = X + (size_t)Nc * S_X;
    float* B1  = Z + (size_t)Nc * S_X;
    float* B2  = B1 + (size_t)Nc * S_B1;
    float* Pp  = B2 + (size_t)Nc * S_B2;

    const int BS = 256;

    for (int m = 0; m < 2; ++m) {
        for (int c0 = 0; c0 < N; c0 += Nc) {
            const float* xc = x + (size_t)c0 * S_X * 2;   // chunk base in [N,C,T,V,M]
            size_t nX = (size_t)Nc * S_X;
            extract_person<<<nblk(nX, BS), BS, 0, stream>>>(xc, X, m, nX);

            // stage-1 convs
            size_t n_c1 = (size_t)Nc * 128 * 112 * 112;
            conv_bn_relu<5, 2><<<nblk(n_c1, BS), BS, 0, stream>>>(
                X, w1, b1, g1, be1, B1, Nc, 3, 224, 224, 128, 112, 112);
            size_t n_c2 = (size_t)Nc * 128 * 56 * 56;
            conv_bn_relu<5, 2><<<nblk(n_c2, BS), BS, 0, stream>>>(
                B1, w2, b2, g2, be2, B2, Nc, 128, 112, 112, 128, 56, 56);
            size_t nP = (size_t)Nc * S_P;
            maxpool2<<<nblk(nP, BS), BS, 0, stream>>>(B2, Pp, Nc * 128, 56, 56);

            // tiny FC -> rotation params
            linear_kernel<<<Nc * 6, BS, 0, stream>>>(Pp, fw, fb, O6, 100352, 6);
            make_rot<<<1, 64, 0, stream>>>(O6, Rm, BV, Nc);
            rot_apply<<<nblk(nX, BS), BS, 0, stream>>>(X, Rm, BV, Z, 224 * 224, nX);

            // backbone: 3->64->256->512->1024->2048, all 3x3 s2 p1
            size_t nb1 = (size_t)Nc * 64 * 112 * 112;
            conv_bn_relu<3, 1><<<nblk(nb1, BS), BS, 0, stream>>>(
                Z, bw[0], nullptr, bg[0], bb[0], B1, Nc, 3, 224, 224, 64, 112, 112);
            size_t nb2 = (size_t)Nc * 256 * 56 * 56;
            conv_bn_relu<3, 1><<<nblk(nb2, BS), BS, 0, stream>>>(
                B1, bw[1], nullptr, bg[1], bb[1], B2, Nc, 64, 112, 112, 256, 56, 56);
            size_t nb3 = (size_t)Nc * 512 * 28 * 28;
            conv_bn_relu<3, 1><<<nblk(nb3, BS), BS, 0, stream>>>(
                B2, bw[2], nullptr, bg[2], bb[2], B1, Nc, 256, 56, 56, 512, 28, 28);
            size_t nb4 = (size_t)Nc * 1024 * 14 * 14;
            conv_bn_relu<3, 1><<<nblk(nb4, BS), BS, 0, stream>>>(
                B1, bw[3], nullptr, bg[3], bb[3], B2, Nc, 512, 28, 28, 1024, 14, 14);
            size_t nb5 = (size_t)Nc * 2048 * 7 * 7;
            conv_bn_relu<3, 1><<<nblk(nb5, BS), BS, 0, stream>>>(
                B2, bw[4], nullptr, bg[4], bb[4], B1, Nc, 1024, 14, 14, 2048, 7, 7);

            float* PMc = PM + (size_t)c0 * S_PM;
            if (m == 0)
                copy_kernel<<<nblk(nb5, BS), BS, 0, stream>>>(B1, PMc, nb5);
            else
                max_kernel<<<nblk(nb5, BS), BS, 0, stream>>>(B1, PMc, nb5);
        }
    }

    // final linear [32,100352] x [60,100352]^T
    linear_kernel<<<N * 60, BS, 0, stream>>>(PM, lw, lb, out, 100352, 60);
}

// Round 3
// 6967.590 us; speedup vs baseline: 27.3227x; 27.3227x over previous
//
#include <hip/hip_runtime.h>
#include <hip/hip_bf16.h>

typedef unsigned short u16;
typedef __attribute__((ext_vector_type(8))) short bf16x8;
typedef __attribute__((ext_vector_type(4))) float f32x4;
typedef __attribute__((ext_vector_type(8))) unsigned short u16x8;

__device__ __forceinline__ u16 f2bf(float v) {
    __hip_bfloat16 b = __float2bfloat16(v);
    return *reinterpret_cast<u16*>(&b);
}
__device__ __forceinline__ float bf2f(u16 u) {
    __hip_bfloat16 b;
    *reinterpret_cast<u16*>(&b) = u;
    return __bfloat162float(b);
}

// ---------------------------------------------------------------------------
// weights fp32 -> bf16 (hi[, lo]) padded to Kp columns
// ---------------------------------------------------------------------------
__global__ void w_to_bf16(const float* __restrict__ w, u16* __restrict__ wh,
                          u16* __restrict__ wl, int Cout, int Kdim, int Kp) {
    int i = blockIdx.x * blockDim.x + threadIdx.x;
    if (i >= Cout * Kp) return;
    int oc = i / Kp, k = i - oc * Kp;
    float v = (k < Kdim) ? w[(size_t)oc * Kdim + k] : 0.f;
    u16 h = f2bf(v);
    wh[i] = h;
    if (wl) wl[i] = f2bf(v - bf2f(h));
}

// ---------------------------------------------------------------------------
// extract person slice -> fp32 X and split bf16 Xh/Xl
// ---------------------------------------------------------------------------
__global__ void extract_person2(const float* __restrict__ x, float* __restrict__ X,
                                u16* __restrict__ Xh, u16* __restrict__ Xl,
                                int m, size_t total) {
    size_t i = (size_t)blockIdx.x * blockDim.x + threadIdx.x;
    if (i >= total) return;
    float v = x[i * 2 + m];
    X[i] = v;
    u16 h = f2bf(v);
    Xh[i] = h;
    Xl[i] = f2bf(v - bf2f(h));
}

// ---------------------------------------------------------------------------
// implicit-GEMM conv via mfma_f32_16x16x32_bf16
//   A = weights [Cout, Kp] (bf16, optional lo plane), M axis = Cout
//   B = im2col gather of input acts (bf16, optional lo), N axis = n*Hout*Wout
//   block tile 64x64, 4 waves each 32x32 (2x2 fragments), BK=32
// SIN: split-precision input (hi/lo acts + weights, 3x MFMA)
// MOUT: 0 = bf16 out, 1 = split bf16 out, 2 = fp32 out
// ---------------------------------------------------------------------------
template <int KS, int P, bool SIN, int MOUT>
__global__ __launch_bounds__(256) void conv_mfma(
    const u16* __restrict__ inh, const u16* __restrict__ inl,
    const u16* __restrict__ wh, const u16* __restrict__ wl,
    const float* __restrict__ cbias, const float* __restrict__ gam,
    const float* __restrict__ bet,
    u16* __restrict__ outh, u16* __restrict__ outl, float* __restrict__ outf,
    int Nn, int Cin, int Hin, int Win, int Cout, int Hout, int Wout,
    int Kdim, int Kp, int bn_blocks) {
    constexpr int KK = KS * KS;
    const int HWin = Hin * Win, HWout = Hout * Wout;
    const int NHW = Nn * HWout;
    const int bm = blockIdx.x / bn_blocks;
    const int bn = blockIdx.x % bn_blocks;
    const int oc0 = bm * 64, s0 = bn * 64;
    const int tid = threadIdx.x;

    __shared__ __align__(16) u16 As[SIN ? 2 : 1][64 * 40];
    __shared__ __align__(16) u16 Bs[SIN ? 2 : 1][64 * 40];
    __shared__ int cbse[64];
    __shared__ short cy[64], cx[64];

    if (tid < 64) {
        int s = s0 + tid;
        bool valid = s < NHW;
        int ss = valid ? s : 0;
        int n = ss / HWout, pos = ss - n * HWout;
        int oy = pos / Wout, ox = pos - oy * Wout;
        cbse[tid] = n * Cin * HWin;
        cy[tid] = valid ? (short)(oy * 2 - P) : (short)-20000;
        cx[tid] = (short)(ox * 2 - P);
    }

    f32x4 acc[2][2] = {};
    const int lane = tid & 63;
    const int wv = tid >> 6;
    const int mq = (wv & 1) * 32, nq = (wv >> 1) * 32;
    const int foff = (lane & 15) * 40 + (lane >> 4) * 8;
    const int aof = mq * 40 + foff;
    const int bof = nq * 40 + foff;
    const int sm = tid & 63, soct = tid >> 6;
    const int stg = sm * 40 + soct * 8;

    __syncthreads();

    const int nsteps = Kp >> 5;
    for (int t = 0; t < nsteps; ++t) {
        if (t) __syncthreads();
        const int k0 = t << 5;
        // ---- stage A (weights) ----
        {
            size_t widx = (size_t)(oc0 + sm) * Kp + k0 + soct * 8;
            *reinterpret_cast<u16x8*>(&As[0][stg]) =
                *reinterpret_cast<const u16x8*>(&wh[widx]);
            if (SIN)
                *reinterpret_cast<u16x8*>(&As[1][stg]) =
                    *reinterpret_cast<const u16x8*>(&wl[widx]);
        }
        // ---- stage B (im2col gather) ----
        {
            const int cb = cbse[sm];
            const int cyy = cy[sm], cxx = cx[sm];
            u16 vh[8], vl[8];
#pragma unroll
            for (int j = 0; j < 8; ++j) {
                int k = k0 + soct * 8 + j;
                int ic = k / KK;
                int r = k - ic * KK;
                int ky = r / KS, kx = r - ky * KS;
                int iy = cyy + ky, ix = cxx + kx;
                bool ok = (k < Kdim) && ((unsigned)iy < (unsigned)Hin) &&
                          ((unsigned)ix < (unsigned)Win);
                int a = cb + ic * HWin + iy * Win + ix;
                vh[j] = ok ? inh[a] : (u16)0;
                if (SIN) vl[j] = ok ? inl[a] : (u16)0;
            }
            *reinterpret_cast<u16x8*>(&Bs[0][stg]) = *reinterpret_cast<u16x8*>(vh);
            if (SIN)
                *reinterpret_cast<u16x8*>(&Bs[1][stg]) = *reinterpret_cast<u16x8*>(vl);
        }
        __syncthreads();
        // ---- fragments + MFMA ----
        bf16x8 ah[2], bh[2];
        ah[0] = *reinterpret_cast<const bf16x8*>(&As[0][aof]);
        ah[1] = *reinterpret_cast<const bf16x8*>(&As[0][aof + 16 * 40]);
        bh[0] = *reinterpret_cast<const bf16x8*>(&Bs[0][bof]);
        bh[1] = *reinterpret_cast<const bf16x8*>(&Bs[0][bof + 16 * 40]);
#pragma unroll
        for (int mi = 0; mi < 2; ++mi)
#pragma unroll
            for (int ni = 0; ni < 2; ++ni)
                acc[mi][ni] = __builtin_amdgcn_mfma_f32_16x16x32_bf16(
                    ah[mi], bh[ni], acc[mi][ni], 0, 0, 0);
        if (SIN) {
            bf16x8 al[2], bl[2];
            al[0] = *reinterpret_cast<const bf16x8*>(&As[1][aof]);
            al[1] = *reinterpret_cast<const bf16x8*>(&As[1][aof + 16 * 40]);
            bl[0] = *reinterpret_cast<const bf16x8*>(&Bs[1][bof]);
            bl[1] = *reinterpret_cast<const bf16x8*>(&Bs[1][bof + 16 * 40]);
#pragma unroll
            for (int mi = 0; mi < 2; ++mi)
#pragma unroll
                for (int ni = 0; ni < 2; ++ni) {
                    acc[mi][ni] = __builtin_amdgcn_mfma_f32_16x16x32_bf16(
                        ah[mi], bl[ni], acc[mi][ni], 0, 0, 0);
                    acc[mi][ni] = __builtin_amdgcn_mfma_f32_16x16x32_bf16(
                        al[mi], bh[ni], acc[mi][ni], 0, 0, 0);
                }
        }
    }

    // ---- epilogue: D row = oc (mq+mi*16+(lane>>4)*4+r), col = s (nq+ni*16+(lane&15))
#pragma unroll
    for (int ni = 0; ni < 2; ++ni) {
        int s = s0 + nq + ni * 16 + (lane & 15);
        if (s >= NHW) continue;
        int n = s / HWout, pos = s - n * HWout;
#pragma unroll
        for (int mi = 0; mi < 2; ++mi) {
#pragma unroll
            for (int r = 0; r < 4; ++r) {
                int oc = oc0 + mq + mi * 16 + (lane >> 4) * 4 + r;
                float v = acc[mi][ni][r];
                if (cbias) v += cbias[oc];
                v = fmaf(v, gam[oc], bet[oc]);
                v = fmaxf(v, 0.f);
                size_t o = (size_t)(n * Cout + oc) * HWout + pos;
                if constexpr (MOUT == 0) {
                    outh[o] = f2bf(v);
                } else if constexpr (MOUT == 1) {
                    u16 h = f2bf(v);
                    outh[o] = h;
                    outl[o] = f2bf(v - bf2f(h));
                } else {
                    outf[o] = v;
                }
            }
        }
    }
}

// ---------------------------------------------------------------------------
// 2x2 maxpool stride 2 (fp32)
// ---------------------------------------------------------------------------
__global__ void maxpool2(const float* __restrict__ in, float* __restrict__ out,
                         int NC, int H, int W) {
    int Ho = H >> 1, Wo = W >> 1;
    size_t idx = (size_t)blockIdx.x * blockDim.x + threadIdx.x;
    size_t total = (size_t)NC * Ho * Wo;
    if (idx >= total) return;
    int ox = idx % Wo;
    size_t t = idx / Wo;
    int oy = t % Ho;
    int nc = t / Ho;
    const float* p = in + ((size_t)nc * H + oy * 2) * W + ox * 2;
    out[idx] = fmaxf(fmaxf(p[0], p[1]), fmaxf(p[W], p[W + 1]));
}

// ---------------------------------------------------------------------------
// row-dot linear (fp32): out[n*Ncols+j] = X[n,:].W[j,:] + bias[j]
// ---------------------------------------------------------------------------
__global__ __launch_bounds__(256) void linear_kernel(
    const float* __restrict__ X, const float* __restrict__ W,
    const float* __restrict__ bias, float* __restrict__ out, int K, int Ncols) {
    int n = blockIdx.x / Ncols;
    int j = blockIdx.x % Ncols;
    const float4* x4 = reinterpret_cast<const float4*>(X + (size_t)n * K);
    const float4* w4 = reinterpret_cast<const float4*>(W + (size_t)j * K);
    int K4 = K >> 2;
    float s = 0.f;
    for (int k = threadIdx.x; k < K4; k += blockDim.x) {
        float4 a = x4[k], b = w4[k];
        s = fmaf(a.x, b.x, s);
        s = fmaf(a.y, b.y, s);
        s = fmaf(a.z, b.z, s);
        s = fmaf(a.w, b.w, s);
    }
#pragma unroll
    for (int off = 32; off > 0; off >>= 1) s += __shfl_down(s, off, 64);
    __shared__ float lds[4];
    int lane = threadIdx.x & 63, wv = threadIdx.x >> 6;
    if (lane == 0) lds[wv] = s;
    __syncthreads();
    if (threadIdx.x == 0)
        out[blockIdx.x] = lds[0] + lds[1] + lds[2] + lds[3] + bias[j];
}

// ---------------------------------------------------------------------------
// rotation matrices + bias vectors from o[Nc,6]
// ---------------------------------------------------------------------------
__global__ void make_rot(const float* __restrict__ o6, float* __restrict__ R,
                         float* __restrict__ bv, int Nc) {
    int n = threadIdx.x;
    if (n >= Nc) return;
    const float PI = 3.14159265358979323846f;
    float a0 = o6[n * 6 + 0] * PI, a1 = o6[n * 6 + 1] * PI, a2 = o6[n * 6 + 2] * PI;
    float c0 = cosf(a0), c1 = cosf(a1), c2 = cosf(a2);
    float s0 = sinf(a0), s1 = sinf(a1), s2 = sinf(a2);
    float Rx[9] = {1, 0, 0, 0, c0, s0, 0, -s0, c0};
    float Ry[9] = {c1, 0, -s1, 0, 1, 0, s1, 0, c1};
    float Rz[9] = {c2, s2, 0, -s2, c2, 0, 0, 0, 1};
    float M[9], Rm[9];
#pragma unroll
    for (int i = 0; i < 3; ++i)
#pragma unroll
        for (int j = 0; j < 3; ++j) {
            float acc = 0.f;
#pragma unroll
            for (int k = 0; k < 3; ++k) acc = fmaf(Ry[i * 3 + k], Rz[k * 3 + j], acc);
            M[i * 3 + j] = acc;
        }
#pragma unroll
    for (int i = 0; i < 3; ++i)
#pragma unroll
        for (int j = 0; j < 3; ++j) {
            float acc = 0.f;
#pragma unroll
            for (int k = 0; k < 3; ++k) acc = fmaf(Rx[i * 3 + k], M[k * 3 + j], acc);
            Rm[i * 3 + j] = acc;
        }
    const float MINV = -3.602826f;
    float v0 = MINV - o6[n * 6 + 3];
    float v1 = MINV - o6[n * 6 + 4];
    float v2 = MINV - o6[n * 6 + 5];
#pragma unroll
    for (int i = 0; i < 3; ++i) {
        float sh = Rm[i * 3 + 0] * v0 + Rm[i * 3 + 1] * v1 + Rm[i * 3 + 2] * v2;
        bv[n * 3 + i] = 255.f * (sh - MINV) / 8.812765f;
        R[n * 9 + i * 3 + 0] = Rm[i * 3 + 0];
        R[n * 9 + i * 3 + 1] = Rm[i * 3 + 1];
        R[n * 9 + i * 3 + 2] = Rm[i * 3 + 2];
    }
}

// ---------------------------------------------------------------------------
// z = R.x + bias, written as bf16
// ---------------------------------------------------------------------------
__global__ void rot_apply(const float* __restrict__ xp, const float* __restrict__ R,
                          const float* __restrict__ bv, u16* __restrict__ z,
                          int HW, size_t total) {
    size_t idx = (size_t)blockIdx.x * blockDim.x + threadIdx.x;
    if (idx >= total) return;
    int p = idx % HW;
    size_t t = idx / HW;
    int i = t % 3;
    int n = t / 3;
    const float* xb = xp + (size_t)n * 3 * HW + p;
    float r0 = R[n * 9 + i * 3 + 0], r1 = R[n * 9 + i * 3 + 1], r2 = R[n * 9 + i * 3 + 2];
    float v = fmaf(r0, xb[0], fmaf(r1, xb[(size_t)HW], fmaf(r2, xb[(size_t)2 * HW], bv[n * 3 + i])));
    z[idx] = f2bf(v);
}

__global__ void copy_kernel(const float* __restrict__ a, float* __restrict__ o, size_t n) {
    size_t i = (size_t)blockIdx.x * blockDim.x + threadIdx.x;
    if (i < n) o[i] = a[i];
}
__global__ void max_kernel(const float* __restrict__ a, float* __restrict__ o, size_t n) {
    size_t i = (size_t)blockIdx.x * blockDim.x + threadIdx.x;
    if (i < n) o[i] = fmaxf(o[i], a[i]);
}

// ---------------------------------------------------------------------------
static inline int nblk(size_t total, int bs) { return (int)((total + bs - 1) / bs); }

extern "C" void kernel_launch(void* const* d_in, const int* in_sizes, int n_in,
                              void* d_out, int out_size, void* d_ws, size_t ws_size,
                              hipStream_t stream) {
    const float* x   = (const float*)d_in[0];
    const float* w1  = (const float*)d_in[1];
    const float* b1  = (const float*)d_in[2];
    const float* g1  = (const float*)d_in[3];
    const float* be1 = (const float*)d_in[4];
    const float* w2  = (const float*)d_in[5];
    const float* b2  = (const float*)d_in[6];
    const float* g2  = (const float*)d_in[7];
    const float* be2 = (const float*)d_in[8];
    const float* fw  = (const float*)d_in[9];
    const float* fb  = (const float*)d_in[10];
    const float* bw[5], *bg[5], *bb[5];
    for (int i = 0; i < 5; ++i) {
        bw[i] = (const float*)d_in[11 + 3 * i];
        bg[i] = (const float*)d_in[12 + 3 * i];
        bb[i] = (const float*)d_in[13 + 3 * i];
    }
    const float* lw = (const float*)d_in[26];
    const float* lb = (const float*)d_in[27];
    float* out = (float*)d_out;

    const int N = 32;
    const int BS = 256;

    // backbone layer geometry
    const int bC[6] = {3, 64, 256, 512, 1024, 2048};
    const int bH[6] = {224, 112, 56, 28, 14, 7};
    // Kdim / Kp per conv
    const int K1d = 75, K1p = 96;
    const int K2d = 3200, K2p = 3200;
    const int Kbd[5] = {27, 576, 2304, 4608, 9216};
    const int Kbp[5] = {32, 576, 2304, 4608, 9216};

    // per-sample buffer sizes (element counts)
    const size_t S_X = 150528;           // fp32
    const size_t S_B1u = 1605632;        // u16 (hi & lo planes)
    const size_t S_B2f = 802816;         // fp32
    const size_t S_Pp = 100352;          // fp32
    // per-sample float-equivalents: X(150528) + Xh+Xl(150528) + Z16(75264)
    //   + B1h+B1l(1605632) + B2f(802816) + Pp(100352)
    const size_t per_sample_f = 2885120;
    size_t wu = (size_t)128 * K1p * 2 + (size_t)128 * K2p * 2;  // split stage-1
    for (int i = 0; i < 5; ++i) wu += (size_t)bC[i + 1] * Kbp[i];
    const size_t fixed_f = (size_t)N * S_Pp + 1024 + (wu + 1) / 2 + 16;

    size_t ws_floats = ws_size / sizeof(float);
    int Nc = N;
    while (Nc > 1 && (size_t)Nc * per_sample_f + fixed_f > ws_floats) Nc >>= 1;

    // ---- carve workspace ----
    char* cur = (char*)d_ws;
    auto alf = [&](size_t n) { float* p = (float*)cur; cur += n * sizeof(float); return p; };
    auto alu = [&](size_t n) { u16* p = (u16*)cur; cur += ((n + 7) & ~(size_t)7) * sizeof(u16); return p; };

    float* PM = alf((size_t)N * S_Pp);
    float* O6 = alf(256);
    float* Rm = alf(384);
    float* BV = alf(384);
    u16* w1h = alu((size_t)128 * K1p);
    u16* w1l = alu((size_t)128 * K1p);
    u16* w2h = alu((size_t)128 * K2p);
    u16* w2l = alu((size_t)128 * K2p);
    u16* wbh[5];
    for (int i = 0; i < 5; ++i) wbh[i] = alu((size_t)bC[i + 1] * Kbp[i]);
    float* X = alf((size_t)Nc * S_X);
    u16* Xh = alu((size_t)Nc * S_X);
    u16* Xl = alu((size_t)Nc * S_X);
    u16* Z16 = alu((size_t)Nc * S_X);
    u16* B1h = alu((size_t)Nc * S_B1u);
    u16* B1l = alu((size_t)Nc * S_B1u);
    float* B2f = alf((size_t)Nc * S_B2f);
    float* Pp = alf((size_t)Nc * S_Pp);

    // ---- weight conversions (every launch; inputs are constant) ----
    w_to_bf16<<<nblk((size_t)128 * K1p, BS), BS, 0, stream>>>(w1, w1h, w1l, 128, K1d, K1p);
    w_to_bf16<<<nblk((size_t)128 * K2p, BS), BS, 0, stream>>>(w2, w2h, w2l, 128, K2d, K2p);
    for (int i = 0; i < 5; ++i)
        w_to_bf16<<<nblk((size_t)bC[i + 1] * Kbp[i], BS), BS, 0, stream>>>(
            bw[i], wbh[i], nullptr, bC[i + 1], Kbd[i], Kbp[i]);

    for (int m = 0; m < 2; ++m) {
        for (int c0 = 0; c0 < N; c0 += Nc) {
            const float* xc = x + (size_t)c0 * S_X * 2;
            size_t nX = (size_t)Nc * S_X;
            extract_person2<<<nblk(nX, BS), BS, 0, stream>>>(xc, X, Xh, Xl, m, nX);

            // conv1: 3->128 5x5 s2 p2, split in, split out
            {
                int NHW = Nc * 112 * 112;
                int bnb = (NHW + 63) / 64;
                conv_mfma<5, 2, true, 1><<<2 * bnb, 256, 0, stream>>>(
                    Xh, Xl, w1h, w1l, b1, g1, be1, B1h, B1l, nullptr,
                    Nc, 3, 224, 224, 128, 112, 112, K1d, K1p, bnb);
            }
            // conv2: 128->128 5x5 s2 p2, split in, fp32 out
            {
                int NHW = Nc * 56 * 56;
                int bnb = (NHW + 63) / 64;
                conv_mfma<5, 2, true, 2><<<2 * bnb, 256, 0, stream>>>(
                    B1h, B1l, w2h, w2l, b2, g2, be2, nullptr, nullptr, B2f,
                    Nc, 128, 112, 112, 128, 56, 56, K2d, K2p, bnb);
            }
            size_t nP = (size_t)Nc * S_Pp;
            maxpool2<<<nblk(nP, BS), BS, 0, stream>>>(B2f, Pp, Nc * 128, 56, 56);
            linear_kernel<<<Nc * 6, BS, 0, stream>>>(Pp, fw, fb, O6, 100352, 6);
            make_rot<<<1, 64, 0, stream>>>(O6, Rm, BV, Nc);
            rot_apply<<<nblk(nX, BS), BS, 0, stream>>>(X, Rm, BV, Z16, 224 * 224, nX);

            // backbone ping-pong: Z16 -> B1h -> B1l -> B1h -> B1l -> Pp(f32)
            const u16* bin = Z16;
            u16* bouts[4] = {B1h, B1l, B1h, B1l};
            for (int L = 0; L < 5; ++L) {
                int Ho = bH[L + 1];
                int NHW = Nc * Ho * Ho;
                int bnb = (NHW + 63) / 64;
                int gm = bC[L + 1] / 64;
                if (L < 4) {
                    conv_mfma<3, 1, false, 0><<<gm * bnb, 256, 0, stream>>>(
                        bin, nullptr, wbh[L], nullptr, nullptr, bg[L], bb[L],
                        bouts[L], nullptr, nullptr,
                        Nc, bC[L], bH[L], bH[L], bC[L + 1], Ho, Ho,
                        Kbd[L], Kbp[L], bnb);
                    bin = bouts[L];
                } else {
                    conv_mfma<3, 1, false, 2><<<gm * bnb, 256, 0, stream>>>(
                        bin, nullptr, wbh[L], nullptr, nullptr, bg[L], bb[L],
                        nullptr, nullptr, Pp,
                        Nc, bC[L], bH[L], bH[L], bC[L + 1], Ho, Ho,
                        Kbd[L], Kbp[L], bnb);
                }
            }

            float* PMc = PM + (size_t)c0 * S_Pp;
            size_t nOut = (size_t)Nc * S_Pp;
            if (m == 0)
                copy_kernel<<<nblk(nOut, BS), BS, 0, stream>>>(Pp, PMc, nOut);
            else
                max_kernel<<<nblk(nOut, BS), BS, 0, stream>>>(Pp, PMc, nOut);
        }
    }

    linear_kernel<<<N * 60, BS, 0, stream>>>(PM, lw, lb, out, 100352, 60);
}

// Round 4
// 3898.946 us; speedup vs baseline: 48.8269x; 1.7870x over previous
//
#include <hip/hip_runtime.h>
#include <hip/hip_bf16.h>

typedef unsigned short u16;
typedef __attribute__((ext_vector_type(8))) short bf16x8;
typedef __attribute__((ext_vector_type(4))) float f32x4;
typedef __attribute__((ext_vector_type(8))) unsigned short u16x8;
typedef __attribute__((ext_vector_type(4))) unsigned short u16x4;

__device__ __forceinline__ u16 f2bf(float v) {
    __hip_bfloat16 b = __float2bfloat16(v);
    return *reinterpret_cast<u16*>(&b);
}
__device__ __forceinline__ float bf2f(u16 u) {
    __hip_bfloat16 b;
    *reinterpret_cast<u16*>(&b) = u;
    return __bfloat162float(b);
}

// ---------------------------------------------------------------------------
// weight repack OIHW fp32 -> [oc][p*Cin+ic] bf16 (hi[,lo]) ; p = ky*KS+kx
// ---------------------------------------------------------------------------
__global__ void repack_w32(const float* __restrict__ w, u16* __restrict__ wh,
                           u16* __restrict__ wl, int Cout, int Cin, int KK) {
    int i = blockIdx.x * blockDim.x + threadIdx.x;
    int tot = Cout * Cin * KK;
    if (i >= tot) return;
    int oc = i / (Cin * KK);
    int r = i - oc * (Cin * KK);
    int p = r / Cin, ic = r - p * Cin;
    float v = w[((size_t)oc * Cin + ic) * KK + p];
    u16 h = f2bf(v);
    size_t o = (size_t)oc * (Cin * KK) + (size_t)p * Cin + ic;
    wh[o] = h;
    if (wl) wl[o] = f2bf(v - bf2f(h));
}

// weight repack OIHW (Cin=3) -> [oc][pp*4+c], pp padded to PP4 positions
__global__ void repack_w4(const float* __restrict__ w, u16* __restrict__ wh,
                          u16* __restrict__ wl, int Cout, int KK, int PP4) {
    int i = blockIdx.x * blockDim.x + threadIdx.x;
    int tot = Cout * PP4 * 4;
    if (i >= tot) return;
    int oc = i / (PP4 * 4);
    int r = i - oc * (PP4 * 4);
    int pp = r >> 2, c = r & 3;
    float v = (pp < KK && c < 3) ? w[((size_t)oc * 3 + c) * KK + pp] : 0.f;
    u16 h = f2bf(v);
    wh[i] = h;
    if (wl) wl[i] = f2bf(v - bf2f(h));
}

// ---------------------------------------------------------------------------
// extract person m: x [n,c,HW,2] chunk -> X (NCHW fp32) + Xh/Xl (NHWC-C4 bf16)
// ---------------------------------------------------------------------------
__global__ void extract_person3(const float* __restrict__ x, float* __restrict__ X,
                                u16* __restrict__ Xh, u16* __restrict__ Xl,
                                int m, int HW, size_t total) {
    size_t idx = (size_t)blockIdx.x * blockDim.x + threadIdx.x;
    if (idx >= total) return;
    int n = idx / HW;
    int p = idx - (size_t)n * HW;
    u16 h[4], l[4];
    h[3] = 0; l[3] = 0;
#pragma unroll
    for (int c = 0; c < 3; ++c) {
        float v = x[(((size_t)(n * 3 + c)) * HW + p) * 2 + m];
        X[((size_t)(n * 3 + c)) * HW + p] = v;
        u16 hh = f2bf(v);
        h[c] = hh;
        l[c] = f2bf(v - bf2f(hh));
    }
    *reinterpret_cast<u16x4*>(&Xh[((size_t)n * HW + p) * 4]) = *reinterpret_cast<u16x4*>(h);
    *reinterpret_cast<u16x4*>(&Xl[((size_t)n * HW + p) * 4]) = *reinterpret_cast<u16x4*>(l);
}

// ---------------------------------------------------------------------------
// implicit-GEMM conv via mfma_f32_16x16x32_bf16, NHWC activations
//   CT=32: k-step = 32 channels at one (ky,kx); CT=4: k-step = 8 pos x 4 chan
//   block tile 64x64, 4 waves each 32x32 (2x2 16x16 frags), BK=32
// SIN: split hi/lo inputs+weights (3x MFMA). MOUT: 0=bf16 NHWC, 1=split bf16
// NHWC, 2=fp32 NCHW
// ---------------------------------------------------------------------------
template <int KS, int P, int CT, bool SIN, int MOUT>
__global__ __launch_bounds__(256) void conv_mfma(
    const u16* __restrict__ inh, const u16* __restrict__ inl,
    const u16* __restrict__ wh, const u16* __restrict__ wl,
    const float* __restrict__ cbias, const float* __restrict__ gam,
    const float* __restrict__ bet,
    u16* __restrict__ outh, u16* __restrict__ outl, float* __restrict__ outf,
    int Nn, int Cin, int Hin, int Win, int Cout, int Hout, int Wout,
    int Kp, int bn_blocks) {
    constexpr int KK = KS * KS;
    const int HWin = Hin * Win, HWout = Hout * Wout;
    const int NHW = Nn * HWout;
    const int bm = blockIdx.x / bn_blocks;
    const int bn = blockIdx.x % bn_blocks;
    const int oc0 = bm * 64, s0 = bn * 64;
    const int tid = threadIdx.x;

    __shared__ __align__(16) u16 As[SIN ? 2 : 1][64 * 40];
    __shared__ __align__(16) u16 Bs[SIN ? 2 : 1][64 * 40];
    __shared__ int cbase[64];
    __shared__ short cys[64], cxs[64];

    if (tid < 64) {
        int s = s0 + tid;
        bool valid = s < NHW;
        int ss = valid ? s : 0;
        int n = ss / HWout, pos = ss - n * HWout;
        int oy = pos / Wout, ox = pos - oy * Wout;
        cbase[tid] = n * HWin;
        cys[tid] = valid ? (short)(oy * 2 - P) : (short)-20000;
        cxs[tid] = (short)(ox * 2 - P);
    }

    f32x4 acc[2][2] = {};
    const int lane = tid & 63, wv = tid >> 6;
    const int mq = (wv & 1) * 32, nq = (wv >> 1) * 32;
    const int foff = (lane & 15) * 40 + (lane >> 4) * 8;
    const int aof = mq * 40 + foff, bof = nq * 40 + foff;
    const int sm = tid & 63, soct = tid >> 6;
    const int stg = sm * 40 + soct * 8;
    const int srow = tid >> 2, q = tid & 3;   // CT32 B-stage mapping

    __syncthreads();

    const int CS = (CT == 32) ? (Cin >> 5) : 1;
    const int PP = (CT == 32) ? KK : (Kp >> 5);
    int step = 0;
    for (int p = 0; p < PP; ++p) {
        for (int cs = 0; cs < CS; ++cs, ++step) {
            if (step) __syncthreads();
            // ---- stage A (weights, coalesced 16B) ----
            {
                size_t widx = (size_t)(oc0 + sm) * Kp + step * 32 + soct * 8;
                *reinterpret_cast<u16x8*>(&As[0][stg]) =
                    *reinterpret_cast<const u16x8*>(&wh[widx]);
                if (SIN)
                    *reinterpret_cast<u16x8*>(&As[1][stg]) =
                        *reinterpret_cast<const u16x8*>(&wl[widx]);
            }
            // ---- stage B (NHWC, coalesced) ----
            if (CT == 32) {
                int ky = p / KS, kx = p - (p / KS) * KS;
                int iy = (int)cys[srow] + ky, ix = (int)cxs[srow] + kx;
                bool ok = ((unsigned)iy < (unsigned)Hin) && ((unsigned)ix < (unsigned)Win);
                size_t a = ((size_t)(cbase[srow] + iy * Win + ix)) * Cin + cs * 32 + q * 8;
                u16x8 vh = {0, 0, 0, 0, 0, 0, 0, 0};
                if (ok) vh = *reinterpret_cast<const u16x8*>(&inh[a]);
                *reinterpret_cast<u16x8*>(&Bs[0][srow * 40 + q * 8]) = vh;
                if (SIN) {
                    u16x8 vl = {0, 0, 0, 0, 0, 0, 0, 0};
                    if (ok) vl = *reinterpret_cast<const u16x8*>(&inl[a]);
                    *reinterpret_cast<u16x8*>(&Bs[1][srow * 40 + q * 8]) = vl;
                }
            } else {  // CT == 4
                int s_ = tid & 63, j = tid >> 6;
#pragma unroll
                for (int e = 0; e < 2; ++e) {
                    int pp = p * 8 + 2 * j + e;
                    int py = pp / KS, px = pp - (pp / KS) * KS;
                    int iy = (int)cys[s_] + py, ix = (int)cxs[s_] + px;
                    bool ok = (pp < KK) && ((unsigned)iy < (unsigned)Hin) &&
                              ((unsigned)ix < (unsigned)Win);
                    size_t a = ((size_t)(cbase[s_] + iy * Win + ix)) * 4;
                    u16x4 vh = {0, 0, 0, 0};
                    if (ok) vh = *reinterpret_cast<const u16x4*>(&inh[a]);
                    *reinterpret_cast<u16x4*>(&Bs[0][s_ * 40 + (2 * j + e) * 4]) = vh;
                    if (SIN) {
                        u16x4 vl = {0, 0, 0, 0};
                        if (ok) vl = *reinterpret_cast<const u16x4*>(&inl[a]);
                        *reinterpret_cast<u16x4*>(&Bs[1][s_ * 40 + (2 * j + e) * 4]) = vl;
                    }
                }
            }
            __syncthreads();
            // ---- fragments + MFMA ----
            bf16x8 ah[2], bh[2];
            ah[0] = *reinterpret_cast<const bf16x8*>(&As[0][aof]);
            ah[1] = *reinterpret_cast<const bf16x8*>(&As[0][aof + 16 * 40]);
            bh[0] = *reinterpret_cast<const bf16x8*>(&Bs[0][bof]);
            bh[1] = *reinterpret_cast<const bf16x8*>(&Bs[0][bof + 16 * 40]);
#pragma unroll
            for (int mi = 0; mi < 2; ++mi)
#pragma unroll
                for (int ni = 0; ni < 2; ++ni)
                    acc[mi][ni] = __builtin_amdgcn_mfma_f32_16x16x32_bf16(
                        ah[mi], bh[ni], acc[mi][ni], 0, 0, 0);
            if (SIN) {
                bf16x8 al[2], bl[2];
                al[0] = *reinterpret_cast<const bf16x8*>(&As[1][aof]);
                al[1] = *reinterpret_cast<const bf16x8*>(&As[1][aof + 16 * 40]);
                bl[0] = *reinterpret_cast<const bf16x8*>(&Bs[1][bof]);
                bl[1] = *reinterpret_cast<const bf16x8*>(&Bs[1][bof + 16 * 40]);
#pragma unroll
                for (int mi = 0; mi < 2; ++mi)
#pragma unroll
                    for (int ni = 0; ni < 2; ++ni) {
                        acc[mi][ni] = __builtin_amdgcn_mfma_f32_16x16x32_bf16(
                            ah[mi], bl[ni], acc[mi][ni], 0, 0, 0);
                        acc[mi][ni] = __builtin_amdgcn_mfma_f32_16x16x32_bf16(
                            al[mi], bh[ni], acc[mi][ni], 0, 0, 0);
                    }
            }
        }
    }

    // ---- epilogue: frag row = oc, col = s ----
#pragma unroll
    for (int ni = 0; ni < 2; ++ni) {
        int s = s0 + nq + ni * 16 + (lane & 15);
        if (s >= NHW) continue;
        const int oc_b = oc0 + mq + (lane >> 4) * 4;
        if constexpr (MOUT == 2) {
            int n = s / HWout, pos = s - n * HWout;
#pragma unroll
            for (int mi = 0; mi < 2; ++mi) {
                int oc = oc_b + mi * 16;
#pragma unroll
                for (int r = 0; r < 4; ++r) {
                    float v = acc[mi][ni][r];
                    if (cbias) v += cbias[oc + r];
                    v = fmaf(v, gam[oc + r], bet[oc + r]);
                    v = fmaxf(v, 0.f);
                    outf[((size_t)n * Cout + oc + r) * HWout + pos] = v;
                }
            }
        } else {
#pragma unroll
            for (int mi = 0; mi < 2; ++mi) {
                int oc = oc_b + mi * 16;
                u16 hh[4], ll[4];
#pragma unroll
                for (int r = 0; r < 4; ++r) {
                    float v = acc[mi][ni][r];
                    if (cbias) v += cbias[oc + r];
                    v = fmaf(v, gam[oc + r], bet[oc + r]);
                    v = fmaxf(v, 0.f);
                    u16 h = f2bf(v);
                    hh[r] = h;
                    if (MOUT == 1) ll[r] = f2bf(v - bf2f(h));
                }
                *reinterpret_cast<u16x4*>(&outh[(size_t)s * Cout + oc]) =
                    *reinterpret_cast<u16x4*>(hh);
                if constexpr (MOUT == 1)
                    *reinterpret_cast<u16x4*>(&outl[(size_t)s * Cout + oc]) =
                        *reinterpret_cast<u16x4*>(ll);
            }
        }
    }
}

// ---------------------------------------------------------------------------
// 2x2 maxpool stride 2 (fp32 NCHW)
// ---------------------------------------------------------------------------
__global__ void maxpool2(const float* __restrict__ in, float* __restrict__ out,
                         int NC, int H, int W) {
    int Ho = H >> 1, Wo = W >> 1;
    size_t idx = (size_t)blockIdx.x * blockDim.x + threadIdx.x;
    size_t total = (size_t)NC * Ho * Wo;
    if (idx >= total) return;
    int ox = idx % Wo;
    size_t t = idx / Wo;
    int oy = t % Ho;
    int nc = t / Ho;
    const float* p = in + ((size_t)nc * H + oy * 2) * W + ox * 2;
    out[idx] = fmaxf(fmaxf(p[0], p[1]), fmaxf(p[W], p[W + 1]));
}

// ---------------------------------------------------------------------------
// row-dot linear (fp32)
// ---------------------------------------------------------------------------
__global__ __launch_bounds__(256) void linear_kernel(
    const float* __restrict__ X, const float* __restrict__ W,
    const float* __restrict__ bias, float* __restrict__ out, int K, int Ncols) {
    int n = blockIdx.x / Ncols;
    int j = blockIdx.x % Ncols;
    const float4* x4 = reinterpret_cast<const float4*>(X + (size_t)n * K);
    const float4* w4 = reinterpret_cast<const float4*>(W + (size_t)j * K);
    int K4 = K >> 2;
    float s = 0.f;
    for (int k = threadIdx.x; k < K4; k += blockDim.x) {
        float4 a = x4[k], b = w4[k];
        s = fmaf(a.x, b.x, s);
        s = fmaf(a.y, b.y, s);
        s = fmaf(a.z, b.z, s);
        s = fmaf(a.w, b.w, s);
    }
#pragma unroll
    for (int off = 32; off > 0; off >>= 1) s += __shfl_down(s, off, 64);
    __shared__ float lds[4];
    int lane = threadIdx.x & 63, wv = threadIdx.x >> 6;
    if (lane == 0) lds[wv] = s;
    __syncthreads();
    if (threadIdx.x == 0)
        out[blockIdx.x] = lds[0] + lds[1] + lds[2] + lds[3] + bias[j];
}

// ---------------------------------------------------------------------------
// rotation matrices + bias vectors from o[Nc,6]
// ---------------------------------------------------------------------------
__global__ void make_rot(const float* __restrict__ o6, float* __restrict__ R,
                         float* __restrict__ bv, int Nc) {
    int n = threadIdx.x;
    if (n >= Nc) return;
    const float PI = 3.14159265358979323846f;
    float a0 = o6[n * 6 + 0] * PI, a1 = o6[n * 6 + 1] * PI, a2 = o6[n * 6 + 2] * PI;
    float c0 = cosf(a0), c1 = cosf(a1), c2 = cosf(a2);
    float s0 = sinf(a0), s1 = sinf(a1), s2 = sinf(a2);
    float Rx[9] = {1, 0, 0, 0, c0, s0, 0, -s0, c0};
    float Ry[9] = {c1, 0, -s1, 0, 1, 0, s1, 0, c1};
    float Rz[9] = {c2, s2, 0, -s2, c2, 0, 0, 0, 1};
    float M[9], Rm[9];
#pragma unroll
    for (int i = 0; i < 3; ++i)
#pragma unroll
        for (int j = 0; j < 3; ++j) {
            float acc = 0.f;
#pragma unroll
            for (int k = 0; k < 3; ++k) acc = fmaf(Ry[i * 3 + k], Rz[k * 3 + j], acc);
            M[i * 3 + j] = acc;
        }
#pragma unroll
    for (int i = 0; i < 3; ++i)
#pragma unroll
        for (int j = 0; j < 3; ++j) {
            float acc = 0.f;
#pragma unroll
            for (int k = 0; k < 3; ++k) acc = fmaf(Rx[i * 3 + k], M[k * 3 + j], acc);
            Rm[i * 3 + j] = acc;
        }
    const float MINV = -3.602826f;
    float v0 = MINV - o6[n * 6 + 3];
    float v1 = MINV - o6[n * 6 + 4];
    float v2 = MINV - o6[n * 6 + 5];
#pragma unroll
    for (int i = 0; i < 3; ++i) {
        float sh = Rm[i * 3 + 0] * v0 + Rm[i * 3 + 1] * v1 + Rm[i * 3 + 2] * v2;
        bv[n * 3 + i] = 255.f * (sh - MINV) / 8.812765f;
        R[n * 9 + i * 3 + 0] = Rm[i * 3 + 0];
        R[n * 9 + i * 3 + 1] = Rm[i * 3 + 1];
        R[n * 9 + i * 3 + 2] = Rm[i * 3 + 2];
    }
}

// ---------------------------------------------------------------------------
// z = R.x + bias -> NHWC-C4 bf16 (one thread per (n,p), 8B store)
// ---------------------------------------------------------------------------
__global__ void rot_apply3(const float* __restrict__ X, const float* __restrict__ R,
                           const float* __restrict__ bv, u16* __restrict__ z,
                           int HW, size_t total) {
    size_t idx = (size_t)blockIdx.x * blockDim.x + threadIdx.x;
    if (idx >= total) return;
    int n = idx / HW;
    int p = idx - (size_t)n * HW;
    const float* xb = X + (size_t)n * 3 * HW + p;
    float x0 = xb[0], x1 = xb[HW], x2 = xb[(size_t)2 * HW];
    u16 o[4];
#pragma unroll
    for (int i = 0; i < 3; ++i) {
        float v = fmaf(R[n * 9 + i * 3 + 0], x0,
                  fmaf(R[n * 9 + i * 3 + 1], x1,
                  fmaf(R[n * 9 + i * 3 + 2], x2, bv[n * 3 + i])));
        o[i] = f2bf(v);
    }
    o[3] = 0;
    *reinterpret_cast<u16x4*>(&z[((size_t)n * HW + p) * 4]) = *reinterpret_cast<u16x4*>(o);
}

__global__ void copy_kernel(const float* __restrict__ a, float* __restrict__ o, size_t n) {
    size_t i = (size_t)blockIdx.x * blockDim.x + threadIdx.x;
    if (i < n) o[i] = a[i];
}
__global__ void max_kernel(const float* __restrict__ a, float* __restrict__ o, size_t n) {
    size_t i = (size_t)blockIdx.x * blockDim.x + threadIdx.x;
    if (i < n) o[i] = fmaxf(o[i], a[i]);
}

// ---------------------------------------------------------------------------
static inline int nblk(size_t total, int bs) { return (int)((total + bs - 1) / bs); }

extern "C" void kernel_launch(void* const* d_in, const int* in_sizes, int n_in,
                              void* d_out, int out_size, void* d_ws, size_t ws_size,
                              hipStream_t stream) {
    const float* x   = (const float*)d_in[0];
    const float* w1  = (const float*)d_in[1];
    const float* b1  = (const float*)d_in[2];
    const float* g1  = (const float*)d_in[3];
    const float* be1 = (const float*)d_in[4];
    const float* w2  = (const float*)d_in[5];
    const float* b2  = (const float*)d_in[6];
    const float* g2  = (const float*)d_in[7];
    const float* be2 = (const float*)d_in[8];
    const float* fw  = (const float*)d_in[9];
    const float* fb  = (const float*)d_in[10];
    const float* bw[5], *bg[5], *bb[5];
    for (int i = 0; i < 5; ++i) {
        bw[i] = (const float*)d_in[11 + 3 * i];
        bg[i] = (const float*)d_in[12 + 3 * i];
        bb[i] = (const float*)d_in[13 + 3 * i];
    }
    const float* lw = (const float*)d_in[26];
    const float* lb = (const float*)d_in[27];
    float* out = (float*)d_out;

    const int N = 32;
    const int BS = 256;

    const int bC[6] = {3, 64, 256, 512, 1024, 2048};
    const int bH[6] = {224, 112, 56, 28, 14, 7};
    // Kp per conv (k-dim padded, element order matches repack kernels)
    const int K1p = 128;              // CT4: 32 pos x 4 ch
    const int K2p = 3200;             // CT32: 25 pos x 128 ch
    const int Kbp[5] = {64, 576, 2304, 4608, 9216};  // bw1 CT4; rest CT32

    // per-sample buffer bytes
    const size_t S_X = 150528;                         // fp32 NCHW
    const size_t S_C4 = 200704;                        // u16 NHWC-C4 (224*224*4)
    const size_t S_B1u = 1605632;                      // u16 NHWC (112*112*128)
    const size_t S_B2f = 401408;                       // fp32 NCHW (128*56*56)
    const size_t S_Pp = 100352;                        // fp32
    const size_t per_sample_B = S_X * 4 + S_C4 * 2 * 3 + S_B1u * 2 * 2 +
                                S_B2f * 4 + S_Pp * 4;  // 10,235,904 B
    size_t wu = (size_t)128 * K1p * 2 + (size_t)128 * K2p * 2;
    for (int i = 0; i < 5; ++i) wu += (size_t)bC[i + 1] * Kbp[i];
    const size_t fixed_B = (size_t)N * S_Pp * 4 + 8192 + wu * 2 + 64;

    int Nc = N;
    while (Nc > 1 && (size_t)Nc * per_sample_B + fixed_B > ws_size) Nc >>= 1;

    // ---- carve workspace ----
    char* cur = (char*)d_ws;
    auto alf = [&](size_t n) { float* p = (float*)cur; cur += n * sizeof(float); return p; };
    auto alu = [&](size_t n) { u16* p = (u16*)cur; cur += ((n + 7) & ~(size_t)7) * sizeof(u16); return p; };

    float* PM = alf((size_t)N * S_Pp);
    float* O6 = alf(256);
    float* Rm = alf(384);
    float* BV = alf(384);
    u16* w1h = alu((size_t)128 * K1p);
    u16* w1l = alu((size_t)128 * K1p);
    u16* w2h = alu((size_t)128 * K2p);
    u16* w2l = alu((size_t)128 * K2p);
    u16* wbh[5];
    for (int i = 0; i < 5; ++i) wbh[i] = alu((size_t)bC[i + 1] * Kbp[i]);
    float* X = alf((size_t)Nc * S_X);
    u16* Xh = alu((size_t)Nc * S_C4);
    u16* Xl = alu((size_t)Nc * S_C4);
    u16* Z16 = alu((size_t)Nc * S_C4);
    u16* B1h = alu((size_t)Nc * S_B1u);
    u16* B1l = alu((size_t)Nc * S_B1u);
    float* B2f = alf((size_t)Nc * S_B2f);
    float* Pp = alf((size_t)Nc * S_Pp);

    // ---- weight repacks ----
    repack_w4<<<nblk((size_t)128 * K1p, BS), BS, 0, stream>>>(w1, w1h, w1l, 128, 25, 32);
    repack_w32<<<nblk((size_t)128 * 128 * 25, BS), BS, 0, stream>>>(w2, w2h, w2l, 128, 128, 25);
    repack_w4<<<nblk((size_t)64 * Kbp[0], BS), BS, 0, stream>>>(bw[0], wbh[0], nullptr, 64, 9, 16);
    for (int i = 1; i < 5; ++i)
        repack_w32<<<nblk((size_t)bC[i + 1] * bC[i] * 9, BS), BS, 0, stream>>>(
            bw[i], wbh[i], nullptr, bC[i + 1], bC[i], 9);

    for (int m = 0; m < 2; ++m) {
        for (int c0 = 0; c0 < N; c0 += Nc) {
            const float* xc = x + (size_t)c0 * S_X * 2;
            size_t nNP = (size_t)Nc * 224 * 224;
            extract_person3<<<nblk(nNP, BS), BS, 0, stream>>>(xc, X, Xh, Xl, m, 224 * 224, nNP);

            // conv1: 3->128 5x5 s2 p2 (CT4, split, split-out NHWC)
            {
                int NHW = Nc * 112 * 112;
                int bnb = (NHW + 63) / 64;
                conv_mfma<5, 2, 4, true, 1><<<2 * bnb, 256, 0, stream>>>(
                    Xh, Xl, w1h, w1l, b1, g1, be1, B1h, B1l, nullptr,
                    Nc, 4, 224, 224, 128, 112, 112, K1p, bnb);
            }
            // conv2: 128->128 5x5 s2 p2 (CT32, split, fp32 NCHW out)
            {
                int NHW = Nc * 56 * 56;
                int bnb = (NHW + 63) / 64;
                conv_mfma<5, 2, 32, true, 2><<<2 * bnb, 256, 0, stream>>>(
                    B1h, B1l, w2h, w2l, b2, g2, be2, nullptr, nullptr, B2f,
                    Nc, 128, 112, 112, 128, 56, 56, K2p, bnb);
            }
            size_t nP = (size_t)Nc * S_Pp;
            maxpool2<<<nblk(nP, BS), BS, 0, stream>>>(B2f, Pp, Nc * 128, 56, 56);
            linear_kernel<<<Nc * 6, BS, 0, stream>>>(Pp, fw, fb, O6, 100352, 6);
            make_rot<<<1, 64, 0, stream>>>(O6, Rm, BV, Nc);
            rot_apply3<<<nblk(nNP, BS), BS, 0, stream>>>(X, Rm, BV, Z16, 224 * 224, nNP);

            // backbone
            const u16* bin = Z16;
            u16* bouts[4] = {B1h, B1l, B1h, B1l};
            for (int L = 0; L < 5; ++L) {
                int Ho = bH[L + 1];
                int NHW = Nc * Ho * Ho;
                int bnb = (NHW + 63) / 64;
                int gm = bC[L + 1] / 64;
                if (L == 0) {
                    conv_mfma<3, 1, 4, false, 0><<<gm * bnb, 256, 0, stream>>>(
                        bin, nullptr, wbh[0], nullptr, nullptr, bg[0], bb[0],
                        bouts[0], nullptr, nullptr,
                        Nc, 4, 224, 224, 64, Ho, Ho, Kbp[0], bnb);
                    bin = bouts[0];
                } else if (L < 4) {
                    conv_mfma<3, 1, 32, false, 0><<<gm * bnb, 256, 0, stream>>>(
                        bin, nullptr, wbh[L], nullptr, nullptr, bg[L], bb[L],
                        bouts[L], nullptr, nullptr,
                        Nc, bC[L], bH[L], bH[L], bC[L + 1], Ho, Ho, Kbp[L], bnb);
                    bin = bouts[L];
                } else {
                    conv_mfma<3, 1, 32, false, 2><<<gm * bnb, 256, 0, stream>>>(
                        bin, nullptr, wbh[4], nullptr, nullptr, bg[4], bb[4],
                        nullptr, nullptr, Pp,
                        Nc, bC[4], bH[4], bH[4], bC[5], Ho, Ho, Kbp[4], bnb);
                }
            }

            float* PMc = PM + (size_t)c0 * S_Pp;
            size_t nOut = (size_t)Nc * S_Pp;
            if (m == 0)
                copy_kernel<<<nblk(nOut, BS), BS, 0, stream>>>(Pp, PMc, nOut);
            else
                max_kernel<<<nblk(nOut, BS), BS, 0, stream>>>(Pp, PMc, nOut);
        }
    }

    linear_kernel<<<N * 60, BS, 0, stream>>>(PM, lw, lb, out, 100352, 60);
}